// Round 2
// 824.825 us; speedup vs baseline: 1.0543x; 1.0543x over previous
//
#include <hip/hip_runtime.h>

#define D 64
#define EPS 1e-5f

typedef __bf16 bf16x8 __attribute__((ext_vector_type(8)));
typedef float  f32x4  __attribute__((ext_vector_type(4)));

#define MFMA(a, b, c) __builtin_amdgcn_mfma_f32_16x16x32_bf16((a), (b), (c), 0, 0, 0)

static inline int imin(int a, int b) { return a < b ? a : b; }

// ---------------------------------------------------------------------------
// Pass 1: h = relu(in @ W + b). No LDS, no barriers: each wave owns 32 rows,
// loads A fragments direct-to-register (f32), converts to bf16, MFMAs.
// h is stored as bf16 in MFMA C-fragment layout into hout: each 16-row mtile
// owns a 4096-byte block (== its eventual f32 output region); lane stores its
// 16 values ([nt*4+r] order) at block + lane*32B (first 2048B of the block).
// Per-feature sum/sumsq accumulated in registers -> shfl -> atomics.
// ---------------------------------------------------------------------------
template <bool NTLOAD>
__global__ void __launch_bounds__(256) fused_h_stats_kernel(
    const float* __restrict__ in, const float* __restrict__ W,
    const float* __restrict__ bias, int nrows,
    float* __restrict__ stats, __bf16* __restrict__ hout)
{
    const int tid = threadIdx.x;
    const int lane = tid & 63, wv = tid >> 6;
    const int q = lane >> 4, l16 = lane & 15;

    // B fragments: Bf[ks][nt][j] = W[(ks*32 + q*8 + j)][nt*16 + l16]
    bf16x8 Bf[2][4];
#pragma unroll
    for (int ks = 0; ks < 2; ++ks)
#pragma unroll
      for (int nt = 0; nt < 4; ++nt)
#pragma unroll
        for (int j = 0; j < 8; ++j)
          Bf[ks][nt][j] = (__bf16)W[(ks * 32 + q * 8 + j) * 64 + nt * 16 + l16];

    float bc[4];
#pragma unroll
    for (int nt = 0; nt < 4; ++nt) bc[nt] = bias[nt * 16 + l16];

    float s[4] = {0.f, 0.f, 0.f, 0.f}, sq[4] = {0.f, 0.f, 0.f, 0.f};
    const f32x4 ZERO = {0.f, 0.f, 0.f, 0.f};

    const int ntiles = (nrows + 31) >> 5;      // 32-row wave tiles
    const int stride = gridDim.x << 2;
    for (int t = (blockIdx.x << 2) + wv; t < ntiles; t += stride) {
        // A loads: lane (q,l16) reads rows (t*32 + mt*16 + l16), k = ks*32+q*8..+7
        f32x4 st[2][2][2];
#pragma unroll
        for (int mt = 0; mt < 2; ++mt) {
            int arow = (t << 5) + mt * 16 + l16;
            arow = arow < nrows ? arow : nrows - 1;   // clamp (tail only)
            const float* p = in + (size_t)arow * 64 + q * 8;
#pragma unroll
            for (int ks = 0; ks < 2; ++ks) {
                if (NTLOAD) {
                    st[mt][ks][0] = __builtin_nontemporal_load((const f32x4*)(p + ks * 32));
                    st[mt][ks][1] = __builtin_nontemporal_load((const f32x4*)(p + ks * 32 + 4));
                } else {
                    st[mt][ks][0] = *(const f32x4*)(p + ks * 32);
                    st[mt][ks][1] = *(const f32x4*)(p + ks * 32 + 4);
                }
            }
        }

        bf16x8 af[2][2];
#pragma unroll
        for (int mt = 0; mt < 2; ++mt)
#pragma unroll
          for (int ks = 0; ks < 2; ++ks)
#pragma unroll
            for (int j = 0; j < 8; ++j)
              af[mt][ks][j] = (__bf16)st[mt][ks][j >> 2][j & 3];

        f32x4 acc[2][4];
#pragma unroll
        for (int mt = 0; mt < 2; ++mt)
#pragma unroll
          for (int nt = 0; nt < 4; ++nt) {
            acc[mt][nt] = MFMA(af[mt][0], Bf[0][nt], ZERO);
            acc[mt][nt] = MFMA(af[mt][1], Bf[1][nt], acc[mt][nt]);
          }

#pragma unroll
        for (int mt = 0; mt < 2; ++mt) {
            bf16x8 hh[2];
#pragma unroll
            for (int nt = 0; nt < 4; ++nt)
#pragma unroll
              for (int r = 0; r < 4; ++r) {
                const int row = (t << 5) + mt * 16 + q * 4 + r;
                float h = fmaxf(acc[mt][nt][r] + bc[nt], 0.f);
                if (row < nrows) { s[nt] += h; sq[nt] = fmaf(h, h, sq[nt]); }
                hh[nt >> 1][(nt & 1) * 4 + r] = (__bf16)h;
              }
            if (((2 * t + mt) << 4) < nrows) {
                __bf16* dst = hout + ((size_t)(2 * t + mt) * 2048 + lane * 16);
                *(bf16x8*)dst = hh[0];
                *(bf16x8*)(dst + 8) = hh[1];
            }
        }
    }

#pragma unroll
    for (int nt = 0; nt < 4; ++nt) {
        s[nt]  += __shfl_xor(s[nt], 16, 64);  s[nt]  += __shfl_xor(s[nt], 32, 64);
        sq[nt] += __shfl_xor(sq[nt], 16, 64); sq[nt] += __shfl_xor(sq[nt], 32, 64);
    }
    if (q == 0) {
#pragma unroll
        for (int nt = 0; nt < 4; ++nt) {
            atomicAdd(&stats[nt * 16 + l16], s[nt]);
            atomicAdd(&stats[64 + nt * 16 + l16], sq[nt]);
        }
    }
}

// ---------------------------------------------------------------------------
// scale = g*rsqrt(var+eps), shift = be - m*scale. t<64: atom, t>=64: pair.
// ---------------------------------------------------------------------------
__global__ void finalize_stats_kernel(
    const float* __restrict__ stats,
    const float* __restrict__ g_a, const float* __restrict__ be_a,
    const float* __restrict__ g_p, const float* __restrict__ be_p,
    float n_atom, float n_pair, float* __restrict__ params)
{
    const int t = threadIdx.x;
    const int j = t & 63;
    const bool p = t >= 64;
    const float* st = stats + (p ? 128 : 0);
    const float* g  = p ? g_p  : g_a;
    const float* be = p ? be_p : be_a;
    const float cnt = p ? n_pair : n_atom;
    float m = st[j] / cnt;
    float v = st[64 + j] / cnt - m * m;
    float sc = g[j] * rsqrtf(v + EPS);
    float sh = be[j] - m * sc;
    float* pr = params + (p ? 128 : 0);
    pr[j] = sc;
    pr[64 + j] = sh;
}

// ---------------------------------------------------------------------------
// Atom pass 2 (in place): read h frags (bf16, first 2048B of each 4KB mtile
// block of `out`), write affine'd f32 over the full block. s_waitcnt vmcnt(0)
// before stores: within a block the f32 writes overlap OTHER lanes' bf16 read
// ranges, and TBAA would otherwise allow stores to race in-flight loads.
// ---------------------------------------------------------------------------
__global__ void __launch_bounds__(256) apply_atom_kernel(
    float* __restrict__ out, const float* __restrict__ params, int nrows)
{
    const int tid = threadIdx.x;
    const int lane = tid & 63, wv = tid >> 6;
    const int q = lane >> 4, l16 = lane & 15;

    float sc[4], sh[4];
#pragma unroll
    for (int nt = 0; nt < 4; ++nt) {
        sc[nt] = params[nt * 16 + l16];
        sh[nt] = params[64 + nt * 16 + l16];
    }

    const int ntiles = (nrows + 15) >> 4;
    const int stride = gridDim.x << 2;
    for (int t = (blockIdx.x << 2) + wv; t < ntiles; t += stride) {
        const __bf16* src = (const __bf16*)out + ((size_t)t * 2048 + lane * 16);
        bf16x8 h0 = *(const bf16x8*)src;
        bf16x8 h1 = *(const bf16x8*)(src + 8);
        asm volatile("s_waitcnt vmcnt(0)" ::: "memory");
#pragma unroll
        for (int nt = 0; nt < 4; ++nt)
#pragma unroll
          for (int r = 0; r < 4; ++r) {
            const int row = (t << 4) + q * 4 + r;
            float h = (float)((nt < 2) ? h0[nt * 4 + r] : h1[(nt - 2) * 4 + r]);
            if (row < nrows)
                __builtin_nontemporal_store(fmaf(h, sc[nt], sh[nt]),
                                            out + (size_t)row * 64 + nt * 16 + l16);
          }
    }
}

// ---------------------------------------------------------------------------
// Pair pass 2 (in place): out[e] = affine(h_frag) + [x[send]||x[recv]] @ Wa + ba.
// One wave per 16-edge mtile; gathers direct-to-register (x is L2/L3 resident);
// K=128 MFMA with Wa held in 64 VGPRs. No LDS, no barriers.
// ---------------------------------------------------------------------------
__global__ void __launch_bounds__(256) pair_pass2_kernel(
    float* __restrict__ out, const float* __restrict__ x,
    const int* __restrict__ pidx,
    const float* __restrict__ Wa, const float* __restrict__ ba,
    int E, const float* __restrict__ params)
{
    const int tid = threadIdx.x;
    const int lane = tid & 63, wv = tid >> 6;
    const int q = lane >> 4, l16 = lane & 15;

    bf16x8 B2[4][4];
#pragma unroll
    for (int ks = 0; ks < 4; ++ks)
#pragma unroll
      for (int nt = 0; nt < 4; ++nt)
#pragma unroll
        for (int j = 0; j < 8; ++j)
          B2[ks][nt][j] = (__bf16)Wa[(ks * 32 + q * 8 + j) * 64 + nt * 16 + l16];

    float bac[4], sc[4], sh[4];
#pragma unroll
    for (int nt = 0; nt < 4; ++nt) {
        bac[nt] = ba[nt * 16 + l16];
        sc[nt]  = params[nt * 16 + l16];
        sh[nt]  = params[64 + nt * 16 + l16];
    }

    const f32x4 ZERO = {0.f, 0.f, 0.f, 0.f};

    const int ntiles = E >> 4;                 // E divisible by 16
    const int stride = gridDim.x << 2;
    for (int t = (blockIdx.x << 2) + wv; t < ntiles; t += stride) {
        const int e0 = t << 4;
        const int se = pidx[e0 + l16];
        const int re = pidx[E + e0 + l16];
        const float* ps = x + (size_t)se * 64 + q * 8;
        const float* pr = x + (size_t)re * 64 + q * 8;

        f32x4 g[4][2];                         // ks 0,1 = send; 2,3 = recv
        g[0][0] = *(const f32x4*)ps;          g[0][1] = *(const f32x4*)(ps + 4);
        g[1][0] = *(const f32x4*)(ps + 32);   g[1][1] = *(const f32x4*)(ps + 36);
        g[2][0] = *(const f32x4*)pr;          g[2][1] = *(const f32x4*)(pr + 4);
        g[3][0] = *(const f32x4*)(pr + 32);   g[3][1] = *(const f32x4*)(pr + 36);

        const __bf16* hsrc = (const __bf16*)out + ((size_t)t * 2048 + lane * 16);
        bf16x8 h0 = *(const bf16x8*)hsrc;
        bf16x8 h1 = *(const bf16x8*)(hsrc + 8);

        bf16x8 af[4];
#pragma unroll
        for (int ks = 0; ks < 4; ++ks)
#pragma unroll
          for (int j = 0; j < 8; ++j)
            af[ks][j] = (__bf16)g[ks][j >> 2][j & 3];

        f32x4 acc[4];
#pragma unroll
        for (int nt = 0; nt < 4; ++nt) acc[nt] = ZERO;
#pragma unroll
        for (int ks = 0; ks < 4; ++ks)
#pragma unroll
          for (int nt = 0; nt < 4; ++nt)
            acc[nt] = MFMA(af[ks], B2[ks][nt], acc[nt]);

        asm volatile("s_waitcnt vmcnt(0)" ::: "memory");   // h loads land before in-place stores
#pragma unroll
        for (int nt = 0; nt < 4; ++nt)
#pragma unroll
          for (int r = 0; r < 4; ++r) {
            float h = (float)((nt < 2) ? h0[nt * 4 + r] : h1[(nt - 2) * 4 + r]);
            float val = fmaf(h, sc[nt], sh[nt]) + acc[nt][r] + bac[nt];
            __builtin_nontemporal_store(val,
                out + (size_t)(e0 + q * 4 + r) * 64 + nt * 16 + l16);
          }
    }
}

extern "C" void kernel_launch(void* const* d_in, const int* in_sizes, int n_in,
                              void* d_out, int out_size, void* d_ws, size_t ws_size,
                              hipStream_t stream) {
    const float* x       = (const float*)d_in[0];
    const float* pf      = (const float*)d_in[1];
    const int*   pidx    = (const int*)d_in[2];
    const float* W_atom  = (const float*)d_in[3];
    const float* b_atom  = (const float*)d_in[4];
    const float* g_atom  = (const float*)d_in[5];
    const float* be_atom = (const float*)d_in[6];
    const float* W_pair  = (const float*)d_in[7];
    const float* b_pair  = (const float*)d_in[8];
    const float* g_pair  = (const float*)d_in[9];
    const float* be_pair = (const float*)d_in[10];
    const float* W_a2p   = (const float*)d_in[11];
    const float* b_a2p   = (const float*)d_in[12];

    const int N = in_sizes[0] / D;
    const int E = in_sizes[1] / D;

    float* out_atom = (float*)d_out;
    float* out_pair = out_atom + (size_t)N * D;

    float* stats  = (float*)d_ws;     // [256]: atom sum/sq @0, pair sum/sq @128
    float* params = stats + 256;      // [256]: atom scale/shift @0, pair @128

    (void)hipMemsetAsync(d_ws, 0, 256 * sizeof(float), stream);

    const int ta = (N + 31) / 32, tp = (E + 31) / 32;
    const int ga = imin((ta + 3) / 4, 2048);
    const int gp = imin((tp + 3) / 4, 2048);

    // Pass 1: GEMM + relu + stats, h memoized (bf16 frags) into the out buffer.
    fused_h_stats_kernel<false><<<ga, 256, 0, stream>>>(
        x, W_atom, b_atom, N, stats, (__bf16*)out_atom);
    fused_h_stats_kernel<true><<<gp, 256, 0, stream>>>(
        pf, W_pair, b_pair, E, stats + 128, (__bf16*)out_pair);

    finalize_stats_kernel<<<1, 128, 0, stream>>>(stats, g_atom, be_atom,
                                                 g_pair, be_pair,
                                                 (float)N, (float)E, params);

    // Pass 2: in-place affine (+ gather GEMM for pairs) from memoized h.
    const int t16a = (N + 15) / 16, t16p = E / 16;
    apply_atom_kernel<<<imin((t16a + 3) / 4, 2048), 256, 0, stream>>>(
        out_atom, params, N);
    pair_pass2_kernel<<<imin((t16p + 3) / 4, 2048), 256, 0, stream>>>(
        out_pair, x, pidx, W_a2p, b_a2p, E, params + 128);
}

// Round 3
// 721.918 us; speedup vs baseline: 1.2045x; 1.1425x over previous
//
#include <hip/hip_runtime.h>

#define D 64
#define EPS 1e-5f

typedef __bf16 bf16x4 __attribute__((ext_vector_type(4)));
typedef __bf16 bf16x8 __attribute__((ext_vector_type(8)));
typedef float  f32x4  __attribute__((ext_vector_type(4)));

#define MFMA(a, b, c) __builtin_amdgcn_mfma_f32_16x16x32_bf16((a), (b), (c), 0, 0, 0)

static inline int imin(int a, int b) { return a < b ? a : b; }

#define LDS_STRIDE 80   // bf16 elems per row: 160B, 16B-aligned rows, ~4-way banks

// ---------------------------------------------------------------------------
// Pass 1: h = relu(in @ W + b), wave-private LDS staging, no barriers.
// Tile = 32 contiguous rows (8KB). Coalesced loads (lane*16B), f32->bf16 in
// reg, stage to this wave's LDS buffer, ds_read_b128 MFMA fragments.
// 2-stage pipeline: tile t+1's loads issue before tile t's MFMA/epilogue.
// h stored as bf16 MFMA C-frags into hout (each 16-row mtile owns a 4KB block,
// lane's 16 values at block + lane*32B). Stats via regs -> shfl -> atomics.
// ---------------------------------------------------------------------------
template <bool NTLOAD>
__global__ void __launch_bounds__(256) fused_h_stats_kernel(
    const float* __restrict__ in, const float* __restrict__ W,
    const float* __restrict__ bias, int nrows,
    float* __restrict__ stats, __bf16* __restrict__ hout)
{
    __shared__ __bf16 lds[4][32 * LDS_STRIDE];
    const int tid = threadIdx.x;
    const int lane = tid & 63, wv = tid >> 6;
    const int q = lane >> 4, l16 = lane & 15;
    __bf16* my = lds[wv];

    // B fragments: Bf[ks][nt][j] = W[(ks*32 + q*8 + j)][nt*16 + l16]
    bf16x8 Bf[2][4];
#pragma unroll
    for (int ks = 0; ks < 2; ++ks)
#pragma unroll
      for (int nt = 0; nt < 4; ++nt)
#pragma unroll
        for (int j = 0; j < 8; ++j)
          Bf[ks][nt][j] = (__bf16)W[(ks * 32 + q * 8 + j) * 64 + nt * 16 + l16];

    float bc[4];
#pragma unroll
    for (int nt = 0; nt < 4; ++nt) bc[nt] = bias[nt * 16 + l16];

    float s[4] = {0.f, 0.f, 0.f, 0.f}, sq[4] = {0.f, 0.f, 0.f, 0.f};
    const f32x4 ZERO = {0.f, 0.f, 0.f, 0.f};

    const int ntiles = (nrows + 31) >> 5;
    const int stride = gridDim.x << 2;

    // Coalesced tile load: piece i = 16B at tile_base + i*1024 + lane*16.
    // Piece i holds row (i*4 + (lane>>4)), cols (lane&15)*4 .. +3.
    auto LOADTILE = [&](int tt, f32x4* ld) {
        const int row0 = tt << 5;
        if (row0 + 32 <= nrows) {
            const float* tb = in + (size_t)row0 * 64 + lane * 4;
#pragma unroll
            for (int i = 0; i < 8; ++i)
                ld[i] = NTLOAD ? __builtin_nontemporal_load((const f32x4*)(tb + i * 256))
                               : *(const f32x4*)(tb + i * 256);
        } else {
#pragma unroll
            for (int i = 0; i < 8; ++i) {
                int row = row0 + i * 4 + (lane >> 4);
                ld[i] = (row < nrows)
                          ? *(const f32x4*)(in + (size_t)row * 64 + (lane & 15) * 4)
                          : ZERO;
            }
        }
    };

    int t = (blockIdx.x << 2) + wv;
    bool valid = t < ntiles;
    f32x4 ld[8];
    if (valid) LOADTILE(t, ld);

    while (valid) {
        // convert current tile (frees ld for prefetch)
        bf16x4 c[8];
#pragma unroll
        for (int i = 0; i < 8; ++i)
#pragma unroll
          for (int j = 0; j < 4; ++j)
            c[i][j] = (__bf16)ld[i][j];

        const int tn = t + stride;
        const bool vn = tn < ntiles;
        if (vn) LOADTILE(tn, ld);   // prefetch next tile; overlaps everything below

        // stage to wave-private LDS
#pragma unroll
        for (int i = 0; i < 8; ++i) {
            int wrow = i * 4 + (lane >> 4);
            *(bf16x4*)&my[wrow * LDS_STRIDE + (lane & 15) * 4] = c[i];
        }

        // fragments: af[mt][ks] = rows mt*16+l16, cols ks*32 + q*8 .. +7
        bf16x8 af[2][2];
#pragma unroll
        for (int mt = 0; mt < 2; ++mt)
#pragma unroll
          for (int ks = 0; ks < 2; ++ks)
            af[mt][ks] = *(const bf16x8*)&my[(mt * 16 + l16) * LDS_STRIDE + ks * 32 + q * 8];

        f32x4 acc[2][4];
#pragma unroll
        for (int mt = 0; mt < 2; ++mt)
#pragma unroll
          for (int nt = 0; nt < 4; ++nt) {
            acc[mt][nt] = MFMA(af[mt][0], Bf[0][nt], ZERO);
            acc[mt][nt] = MFMA(af[mt][1], Bf[1][nt], acc[mt][nt]);
          }

#pragma unroll
        for (int mt = 0; mt < 2; ++mt) {
            bf16x8 hh[2];
#pragma unroll
            for (int nt = 0; nt < 4; ++nt)
#pragma unroll
              for (int r = 0; r < 4; ++r) {
                const int row = (t << 5) + mt * 16 + q * 4 + r;
                float h = fmaxf(acc[mt][nt][r] + bc[nt], 0.f);
                if (row < nrows) { s[nt] += h; sq[nt] = fmaf(h, h, sq[nt]); }
                hh[nt >> 1][(nt & 1) * 4 + r] = (__bf16)h;
              }
            if (((2 * t + mt) << 4) < nrows) {
                __bf16* dst = hout + ((size_t)(2 * t + mt) * 2048 + lane * 16);
                *(bf16x8*)dst = hh[0];
                *(bf16x8*)(dst + 8) = hh[1];
            }
        }

        t = tn; valid = vn;
    }

#pragma unroll
    for (int nt = 0; nt < 4; ++nt) {
        s[nt]  += __shfl_xor(s[nt], 16, 64);  s[nt]  += __shfl_xor(s[nt], 32, 64);
        sq[nt] += __shfl_xor(sq[nt], 16, 64); sq[nt] += __shfl_xor(sq[nt], 32, 64);
    }
    if (q == 0) {
#pragma unroll
        for (int nt = 0; nt < 4; ++nt) {
            atomicAdd(&stats[nt * 16 + l16], s[nt]);
            atomicAdd(&stats[64 + nt * 16 + l16], sq[nt]);
        }
    }
}

// ---------------------------------------------------------------------------
// scale = g*rsqrt(var+eps), shift = be - m*scale. t<64: atom, t>=64: pair.
// ---------------------------------------------------------------------------
__global__ void finalize_stats_kernel(
    const float* __restrict__ stats,
    const float* __restrict__ g_a, const float* __restrict__ be_a,
    const float* __restrict__ g_p, const float* __restrict__ be_p,
    float n_atom, float n_pair, float* __restrict__ params)
{
    const int t = threadIdx.x;
    const int j = t & 63;
    const bool p = t >= 64;
    const float* st = stats + (p ? 128 : 0);
    const float* g  = p ? g_p  : g_a;
    const float* be = p ? be_p : be_a;
    const float cnt = p ? n_pair : n_atom;
    float m = st[j] / cnt;
    float v = st[64 + j] / cnt - m * m;
    float sc = g[j] * rsqrtf(v + EPS);
    float sh = be[j] - m * sc;
    float* pr = params + (p ? 128 : 0);
    pr[j] = sc;
    pr[64 + j] = sh;
}

// ---------------------------------------------------------------------------
// Atom pass 2 (in place): read h frags (bf16, first 2048B of each 4KB mtile
// block of `out`), write affine'd f32 over the full block. s_waitcnt vmcnt(0)
// before stores: f32 writes overlap other lanes' bf16 read ranges.
// ---------------------------------------------------------------------------
__global__ void __launch_bounds__(256) apply_atom_kernel(
    float* __restrict__ out, const float* __restrict__ params, int nrows)
{
    const int tid = threadIdx.x;
    const int lane = tid & 63, wv = tid >> 6;
    const int q = lane >> 4, l16 = lane & 15;

    float sc[4], sh[4];
#pragma unroll
    for (int nt = 0; nt < 4; ++nt) {
        sc[nt] = params[nt * 16 + l16];
        sh[nt] = params[64 + nt * 16 + l16];
    }

    const int ntiles = (nrows + 15) >> 4;
    const int stride = gridDim.x << 2;
    for (int t = (blockIdx.x << 2) + wv; t < ntiles; t += stride) {
        const __bf16* src = (const __bf16*)out + ((size_t)t * 2048 + lane * 16);
        bf16x8 h0 = *(const bf16x8*)src;
        bf16x8 h1 = *(const bf16x8*)(src + 8);
        asm volatile("s_waitcnt vmcnt(0)" ::: "memory");
#pragma unroll
        for (int nt = 0; nt < 4; ++nt)
#pragma unroll
          for (int r = 0; r < 4; ++r) {
            const int row = (t << 4) + q * 4 + r;
            float h = (float)((nt < 2) ? h0[nt * 4 + r] : h1[(nt - 2) * 4 + r]);
            if (row < nrows)
                __builtin_nontemporal_store(fmaf(h, sc[nt], sh[nt]),
                                            out + (size_t)row * 64 + nt * 16 + l16);
          }
    }
}

// ---------------------------------------------------------------------------
// Pair pass 2 (in place): out[e] = affine(h_frag) + [x[send]||x[recv]] @ Wa + ba.
// One wave per 16-edge mtile; gathers direct-to-register (x is L3 resident);
// K=128 MFMA with Wa held in 64 VGPRs. No LDS, no barriers.
// ---------------------------------------------------------------------------
__global__ void __launch_bounds__(256) pair_pass2_kernel(
    float* __restrict__ out, const float* __restrict__ x,
    const int* __restrict__ pidx,
    const float* __restrict__ Wa, const float* __restrict__ ba,
    int E, const float* __restrict__ params)
{
    const int tid = threadIdx.x;
    const int lane = tid & 63, wv = tid >> 6;
    const int q = lane >> 4, l16 = lane & 15;

    bf16x8 B2[4][4];
#pragma unroll
    for (int ks = 0; ks < 4; ++ks)
#pragma unroll
      for (int nt = 0; nt < 4; ++nt)
#pragma unroll
        for (int j = 0; j < 8; ++j)
          B2[ks][nt][j] = (__bf16)Wa[(ks * 32 + q * 8 + j) * 64 + nt * 16 + l16];

    float bac[4], sc[4], sh[4];
#pragma unroll
    for (int nt = 0; nt < 4; ++nt) {
        bac[nt] = ba[nt * 16 + l16];
        sc[nt]  = params[nt * 16 + l16];
        sh[nt]  = params[64 + nt * 16 + l16];
    }

    const f32x4 ZERO = {0.f, 0.f, 0.f, 0.f};

    const int ntiles = E >> 4;                 // E divisible by 16
    const int stride = gridDim.x << 2;
    for (int t = (blockIdx.x << 2) + wv; t < ntiles; t += stride) {
        const int e0 = t << 4;
        const int se = pidx[e0 + l16];
        const int re = pidx[E + e0 + l16];
        const float* ps = x + (size_t)se * 64 + q * 8;
        const float* pr = x + (size_t)re * 64 + q * 8;

        f32x4 g[4][2];                         // ks 0,1 = send; 2,3 = recv
        g[0][0] = *(const f32x4*)ps;          g[0][1] = *(const f32x4*)(ps + 4);
        g[1][0] = *(const f32x4*)(ps + 32);   g[1][1] = *(const f32x4*)(ps + 36);
        g[2][0] = *(const f32x4*)pr;          g[2][1] = *(const f32x4*)(pr + 4);
        g[3][0] = *(const f32x4*)(pr + 32);   g[3][1] = *(const f32x4*)(pr + 36);

        const __bf16* hsrc = (const __bf16*)out + ((size_t)t * 2048 + lane * 16);
        bf16x8 h0 = *(const bf16x8*)hsrc;
        bf16x8 h1 = *(const bf16x8*)(hsrc + 8);

        bf16x8 af[4];
#pragma unroll
        for (int ks = 0; ks < 4; ++ks)
#pragma unroll
          for (int j = 0; j < 8; ++j)
            af[ks][j] = (__bf16)g[ks][j >> 2][j & 3];

        f32x4 acc[4];
#pragma unroll
        for (int nt = 0; nt < 4; ++nt) acc[nt] = ZERO;
#pragma unroll
        for (int ks = 0; ks < 4; ++ks)
#pragma unroll
          for (int nt = 0; nt < 4; ++nt)
            acc[nt] = MFMA(af[ks], B2[ks][nt], acc[nt]);

        asm volatile("s_waitcnt vmcnt(0)" ::: "memory");   // h loads land before in-place stores
#pragma unroll
        for (int nt = 0; nt < 4; ++nt)
#pragma unroll
          for (int r = 0; r < 4; ++r) {
            float h = (float)((nt < 2) ? h0[nt * 4 + r] : h1[(nt - 2) * 4 + r]);
            float val = fmaf(h, sc[nt], sh[nt]) + acc[nt][r] + bac[nt];
            __builtin_nontemporal_store(val,
                out + (size_t)(e0 + q * 4 + r) * 64 + nt * 16 + l16);
          }
    }
}

extern "C" void kernel_launch(void* const* d_in, const int* in_sizes, int n_in,
                              void* d_out, int out_size, void* d_ws, size_t ws_size,
                              hipStream_t stream) {
    const float* x       = (const float*)d_in[0];
    const float* pf      = (const float*)d_in[1];
    const int*   pidx    = (const int*)d_in[2];
    const float* W_atom  = (const float*)d_in[3];
    const float* b_atom  = (const float*)d_in[4];
    const float* g_atom  = (const float*)d_in[5];
    const float* be_atom = (const float*)d_in[6];
    const float* W_pair  = (const float*)d_in[7];
    const float* b_pair  = (const float*)d_in[8];
    const float* g_pair  = (const float*)d_in[9];
    const float* be_pair = (const float*)d_in[10];
    const float* W_a2p   = (const float*)d_in[11];
    const float* b_a2p   = (const float*)d_in[12];

    const int N = in_sizes[0] / D;
    const int E = in_sizes[1] / D;

    float* out_atom = (float*)d_out;
    float* out_pair = out_atom + (size_t)N * D;

    float* stats  = (float*)d_ws;     // [256]: atom sum/sq @0, pair sum/sq @128
    float* params = stats + 256;      // [256]: atom scale/shift @0, pair @128

    (void)hipMemsetAsync(d_ws, 0, 256 * sizeof(float), stream);

    const int ta = (N + 31) / 32, tp = (E + 31) / 32;
    const int ga = imin((ta + 3) / 4, 1024);
    const int gp = imin((tp + 3) / 4, 1024);

    // Pass 1: GEMM + relu + stats, h memoized (bf16 frags) into the out buffer.
    fused_h_stats_kernel<false><<<ga, 256, 0, stream>>>(
        x, W_atom, b_atom, N, stats, (__bf16*)out_atom);
    fused_h_stats_kernel<true><<<gp, 256, 0, stream>>>(
        pf, W_pair, b_pair, E, stats + 128, (__bf16*)out_pair);

    finalize_stats_kernel<<<1, 128, 0, stream>>>(stats, g_atom, be_atom,
                                                 g_pair, be_pair,
                                                 (float)N, (float)E, params);

    // Pass 2: in-place affine (+ gather GEMM for pairs) from memoized h.
    const int t16a = (N + 15) / 16, t16p = E / 16;
    apply_atom_kernel<<<imin((t16a + 3) / 4, 2048), 256, 0, stream>>>(
        out_atom, params, N);
    pair_pass2_kernel<<<imin((t16p + 3) / 4, 2048), 256, 0, stream>>>(
        out_pair, x, pidx, W_a2p, b_a2p, E, params + 128);
}

// Round 4
// 715.626 us; speedup vs baseline: 1.2151x; 1.0088x over previous
//
#include <hip/hip_runtime.h>

#define D 64
#define EPS 1e-5f

typedef __bf16 bf16x4 __attribute__((ext_vector_type(4)));
typedef __bf16 bf16x8 __attribute__((ext_vector_type(8)));
typedef float  f32x4  __attribute__((ext_vector_type(4)));

#define MFMA(a, b, c) __builtin_amdgcn_mfma_f32_16x16x32_bf16((a), (b), (c), 0, 0, 0)

static inline int imin(int a, int b) { return a < b ? a : b; }
static inline int imax(int a, int b) { return a > b ? a : b; }

#define LDS_STRIDE 80   // bf16 elems per row: 160B, 16B-aligned rows, ~4-way banks

// ---------------------------------------------------------------------------
// Pass 1 (merged atom+pair by block range): h = relu(in @ W + b).
// Wave-private LDS staging, no barriers, coalesced NT tile loads, 2-stage
// pipeline. h stored as bf16 MFMA C-frags: mtile m owns hstride elems at
// hout + m*hstride; lane's 16 values at +lane*16 (32B).
// Stats: regs -> shfl -> atomics into stats[+0 atom / +128 pair].
// ---------------------------------------------------------------------------
__global__ void __launch_bounds__(256) pass1_kernel(
    const float* __restrict__ xA, const float* __restrict__ WA,
    const float* __restrict__ bA, int NA,
    const float* __restrict__ xP, const float* __restrict__ WP,
    const float* __restrict__ bP, int NP,
    float* __restrict__ stats, __bf16* __restrict__ hA, __bf16* __restrict__ hP,
    int hstride, int atomBlocks)
{
    __shared__ __bf16 lds[4][32 * LDS_STRIDE];
    const bool isA = (int)blockIdx.x < atomBlocks;
    const float* in   = isA ? xA : xP;
    const float* W    = isA ? WA : WP;
    const float* bias = isA ? bA : bP;
    const int nrows   = isA ? NA : NP;
    float* st         = stats + (isA ? 0 : 128);
    __bf16* hout      = isA ? hA : hP;
    const int bid     = isA ? blockIdx.x : blockIdx.x - atomBlocks;
    const int nblk    = isA ? atomBlocks : gridDim.x - atomBlocks;

    const int tid = threadIdx.x;
    const int lane = tid & 63, wv = tid >> 6;
    const int q = lane >> 4, l16 = lane & 15;
    __bf16* my = lds[wv];

    // B fragments: Bf[ks][nt][j] = W[(ks*32 + q*8 + j)][nt*16 + l16]
    bf16x8 Bf[2][4];
#pragma unroll
    for (int ks = 0; ks < 2; ++ks)
#pragma unroll
      for (int nt = 0; nt < 4; ++nt)
#pragma unroll
        for (int j = 0; j < 8; ++j)
          Bf[ks][nt][j] = (__bf16)W[(ks * 32 + q * 8 + j) * 64 + nt * 16 + l16];

    float bc[4];
#pragma unroll
    for (int nt = 0; nt < 4; ++nt) bc[nt] = bias[nt * 16 + l16];

    float s[4] = {0.f, 0.f, 0.f, 0.f}, sq[4] = {0.f, 0.f, 0.f, 0.f};
    const f32x4 ZERO = {0.f, 0.f, 0.f, 0.f};

    const int ntiles = (nrows + 31) >> 5;
    const int stride = nblk << 2;

    // Coalesced tile load: piece i = 16B at tile_base + i*1024 + lane*16.
    auto LOADTILE = [&](int tt, f32x4* ld) {
        const int row0 = tt << 5;
        if (row0 + 32 <= nrows) {
            const float* tb = in + (size_t)row0 * 64 + lane * 4;
#pragma unroll
            for (int i = 0; i < 8; ++i)
                ld[i] = __builtin_nontemporal_load((const f32x4*)(tb + i * 256));
        } else {
#pragma unroll
            for (int i = 0; i < 8; ++i) {
                int row = row0 + i * 4 + (lane >> 4);
                ld[i] = (row < nrows)
                          ? *(const f32x4*)(in + (size_t)row * 64 + (lane & 15) * 4)
                          : ZERO;
            }
        }
    };

    int t = (bid << 2) + wv;
    bool valid = t < ntiles;
    f32x4 ld[8];
    if (valid) LOADTILE(t, ld);

    while (valid) {
        bf16x4 c[8];
#pragma unroll
        for (int i = 0; i < 8; ++i)
#pragma unroll
          for (int j = 0; j < 4; ++j)
            c[i][j] = (__bf16)ld[i][j];

        const int tn = t + stride;
        const bool vn = tn < ntiles;
        if (vn) LOADTILE(tn, ld);   // prefetch next tile

        // stage to wave-private LDS
#pragma unroll
        for (int i = 0; i < 8; ++i) {
            int wrow = i * 4 + (lane >> 4);
            *(bf16x4*)&my[wrow * LDS_STRIDE + (lane & 15) * 4] = c[i];
        }

        bf16x8 af[2][2];
#pragma unroll
        for (int mt = 0; mt < 2; ++mt)
#pragma unroll
          for (int ks = 0; ks < 2; ++ks)
            af[mt][ks] = *(const bf16x8*)&my[(mt * 16 + l16) * LDS_STRIDE + ks * 32 + q * 8];

        f32x4 acc[2][4];
#pragma unroll
        for (int mt = 0; mt < 2; ++mt)
#pragma unroll
          for (int nt = 0; nt < 4; ++nt) {
            acc[mt][nt] = MFMA(af[mt][0], Bf[0][nt], ZERO);
            acc[mt][nt] = MFMA(af[mt][1], Bf[1][nt], acc[mt][nt]);
          }

#pragma unroll
        for (int mt = 0; mt < 2; ++mt) {
            bf16x8 hh[2];
#pragma unroll
            for (int nt = 0; nt < 4; ++nt)
#pragma unroll
              for (int r = 0; r < 4; ++r) {
                const int row = (t << 5) + mt * 16 + q * 4 + r;
                float h = fmaxf(acc[mt][nt][r] + bc[nt], 0.f);
                if (row < nrows) { s[nt] += h; sq[nt] = fmaf(h, h, sq[nt]); }
                hh[nt >> 1][(nt & 1) * 4 + r] = (__bf16)h;
              }
            if (((2 * t + mt) << 4) < nrows) {
                __bf16* dst = hout + ((size_t)(2 * t + mt) * hstride + lane * 16);
                *(bf16x8*)dst = hh[0];
                *(bf16x8*)(dst + 8) = hh[1];
            }
        }

        t = tn; valid = vn;
    }

#pragma unroll
    for (int nt = 0; nt < 4; ++nt) {
        s[nt]  += __shfl_xor(s[nt], 16, 64);  s[nt]  += __shfl_xor(s[nt], 32, 64);
        sq[nt] += __shfl_xor(sq[nt], 16, 64); sq[nt] += __shfl_xor(sq[nt], 32, 64);
    }
    if (q == 0) {
#pragma unroll
        for (int nt = 0; nt < 4; ++nt) {
            atomicAdd(&st[nt * 16 + l16], s[nt]);
            atomicAdd(&st[64 + nt * 16 + l16], sq[nt]);
        }
    }
}

// ---------------------------------------------------------------------------
// scale = g*rsqrt(var+eps), shift = be - m*scale. t<64: atom, t>=64: pair.
// ---------------------------------------------------------------------------
__global__ void finalize_stats_kernel(
    const float* __restrict__ stats,
    const float* __restrict__ g_a, const float* __restrict__ be_a,
    const float* __restrict__ g_p, const float* __restrict__ be_p,
    float n_atom, float n_pair, float* __restrict__ params)
{
    const int t = threadIdx.x;
    const int j = t & 63;
    const bool p = t >= 64;
    const float* st = stats + (p ? 128 : 0);
    const float* g  = p ? g_p  : g_a;
    const float* be = p ? be_p : be_a;
    const float cnt = p ? n_pair : n_atom;
    float m = st[j] / cnt;
    float v = st[64 + j] / cnt - m * m;
    float sc = g[j] * rsqrtf(v + EPS);
    float sh = be[j] - m * sc;
    float* pr = params + (p ? 128 : 0);
    pr[j] = sc;
    pr[64 + j] = sh;
}

// ---------------------------------------------------------------------------
// Pass 2 (merged by block range).
// Atom side: out = affine(h).  Pair side: out = affine(h) + gatherGEMM, with a
// 2-deep software pipeline (idx 2 tiles ahead; gathers + h 1 tile ahead).
// inplace=1 fallback (h lives inside out): drain vmcnt before stores.
// ---------------------------------------------------------------------------
__global__ void __launch_bounds__(256) pass2_kernel(
    float* __restrict__ outA, const __bf16* __restrict__ hA, int NA,
    float* __restrict__ outP, const __bf16* __restrict__ hP, int EP,
    const float* __restrict__ x, const int* __restrict__ pidx,
    const float* __restrict__ Wa, const float* __restrict__ ba,
    const float* __restrict__ params, int hstride, int atomBlocks, int inplace)
{
    const bool isA = (int)blockIdx.x < atomBlocks;
    const int bid  = isA ? blockIdx.x : blockIdx.x - atomBlocks;
    const int nblk = isA ? atomBlocks : gridDim.x - atomBlocks;
    const int tid = threadIdx.x;
    const int lane = tid & 63, wv = tid >> 6;
    const int q = lane >> 4, l16 = lane & 15;
    const int stride = nblk << 2;
    const f32x4 ZERO = {0.f, 0.f, 0.f, 0.f};

    const float* pp = params + (isA ? 0 : 128);
    float sc[4], sh[4];
#pragma unroll
    for (int nt = 0; nt < 4; ++nt) {
        sc[nt] = pp[nt * 16 + l16];
        sh[nt] = pp[64 + nt * 16 + l16];
    }

    if (isA) {
        const int ntiles = (NA + 15) >> 4;
        for (int t = (bid << 2) + wv; t < ntiles; t += stride) {
            const __bf16* src = hA + ((size_t)t * hstride + lane * 16);
            bf16x8 h0 = *(const bf16x8*)src;
            bf16x8 h1 = *(const bf16x8*)(src + 8);
            if (inplace) asm volatile("s_waitcnt vmcnt(0)" ::: "memory");
#pragma unroll
            for (int nt = 0; nt < 4; ++nt)
#pragma unroll
              for (int r = 0; r < 4; ++r) {
                const int row = (t << 4) + q * 4 + r;
                float h = (float)((nt < 2) ? h0[nt * 4 + r] : h1[(nt - 2) * 4 + r]);
                if (row < NA)
                    __builtin_nontemporal_store(fmaf(h, sc[nt], sh[nt]),
                                                outA + (size_t)row * 64 + nt * 16 + l16);
              }
        }
        return;
    }

    // ---- pair side ----
    bf16x8 B2[4][4];
#pragma unroll
    for (int ks = 0; ks < 4; ++ks)
#pragma unroll
      for (int nt = 0; nt < 4; ++nt)
#pragma unroll
        for (int j = 0; j < 8; ++j)
          B2[ks][nt][j] = (__bf16)Wa[(ks * 32 + q * 8 + j) * 64 + nt * 16 + l16];

    float bac[4];
#pragma unroll
    for (int nt = 0; nt < 4; ++nt) bac[nt] = ba[nt * 16 + l16];

    auto GATHER = [&](f32x4 (*g)[2], int se, int re) {
        const float* ps = x + (size_t)se * 64 + q * 8;
        const float* pr = x + (size_t)re * 64 + q * 8;
        g[0][0] = *(const f32x4*)ps;        g[0][1] = *(const f32x4*)(ps + 4);
        g[1][0] = *(const f32x4*)(ps + 32); g[1][1] = *(const f32x4*)(ps + 36);
        g[2][0] = *(const f32x4*)pr;        g[2][1] = *(const f32x4*)(pr + 4);
        g[3][0] = *(const f32x4*)(pr + 32); g[3][1] = *(const f32x4*)(pr + 36);
    };

    const int ntiles = EP >> 4;                // E divisible by 16
    int t = (bid << 2) + wv;
    if (t >= ntiles) return;

    int se = pidx[(t << 4) + l16];
    int re = pidx[EP + (t << 4) + l16];
    int tn = t + stride;
    bool vn = tn < ntiles;
    int sen = 0, ren = 0;
    if (vn) { sen = pidx[(tn << 4) + l16]; ren = pidx[EP + (tn << 4) + l16]; }

    f32x4 g[4][2];
    GATHER(g, se, re);
    const __bf16* hs = hP + ((size_t)t * hstride + lane * 16);
    bf16x8 hc0 = *(const bf16x8*)hs;
    bf16x8 hc1 = *(const bf16x8*)(hs + 8);
    bf16x8 hn0, hn1;

    for (;;) {
        f32x4 acc[4];
#pragma unroll
        for (int nt = 0; nt < 4; ++nt) acc[nt] = ZERO;
#pragma unroll
        for (int ks = 0; ks < 4; ++ks) {
            bf16x8 a;
#pragma unroll
            for (int j = 0; j < 8; ++j) a[j] = (__bf16)g[ks][j >> 2][j & 3];
#pragma unroll
            for (int nt = 0; nt < 4; ++nt) acc[nt] = MFMA(a, B2[ks][nt], acc[nt]);
        }

        // prefetch next tile's gathers + h (g regs are free after cvt)
        if (vn) {
            GATHER(g, sen, ren);
            const __bf16* hsn = hP + ((size_t)tn * hstride + lane * 16);
            hn0 = *(const bf16x8*)hsn;
            hn1 = *(const bf16x8*)(hsn + 8);
        }
        // prefetch idx two tiles ahead
        const int tnn = tn + stride;
        if (tnn < ntiles) {
            sen = pidx[(tnn << 4) + l16];
            ren = pidx[EP + (tnn << 4) + l16];
        }

        if (inplace) asm volatile("s_waitcnt vmcnt(0)" ::: "memory");
        const int e0 = t << 4;
#pragma unroll
        for (int nt = 0; nt < 4; ++nt)
#pragma unroll
          for (int r = 0; r < 4; ++r) {
            float h = (float)((nt < 2) ? hc0[nt * 4 + r] : hc1[(nt - 2) * 4 + r]);
            float val = fmaf(h, sc[nt], sh[nt]) + acc[nt][r] + bac[nt];
            __builtin_nontemporal_store(val,
                outP + (size_t)(e0 + q * 4 + r) * 64 + nt * 16 + l16);
          }

        if (!vn) break;
        t = tn; tn = tnn; vn = tnn < ntiles;
        hc0 = hn0; hc1 = hn1;
    }
}

extern "C" void kernel_launch(void* const* d_in, const int* in_sizes, int n_in,
                              void* d_out, int out_size, void* d_ws, size_t ws_size,
                              hipStream_t stream) {
    const float* x       = (const float*)d_in[0];
    const float* pf      = (const float*)d_in[1];
    const int*   pidx    = (const int*)d_in[2];
    const float* W_atom  = (const float*)d_in[3];
    const float* b_atom  = (const float*)d_in[4];
    const float* g_atom  = (const float*)d_in[5];
    const float* be_atom = (const float*)d_in[6];
    const float* W_pair  = (const float*)d_in[7];
    const float* b_pair  = (const float*)d_in[8];
    const float* g_pair  = (const float*)d_in[9];
    const float* be_pair = (const float*)d_in[10];
    const float* W_a2p   = (const float*)d_in[11];
    const float* b_a2p   = (const float*)d_in[12];

    const int N = in_sizes[0] / D;
    const int E = in_sizes[1] / D;

    float* out_atom = (float*)d_out;
    float* out_pair = out_atom + (size_t)N * D;

    float* stats  = (float*)d_ws;     // [256]: atom sum/sq @0, pair sum/sq @128
    float* params = stats + 256;      // [256]: atom scale/shift @0, pair @128

    // h placement: workspace if it fits (removes in-place store/load hazard),
    // else fall back to in-place inside the out buffer.
    const size_t mA = (size_t)((N + 15) / 16), mP = (size_t)(E / 16);
    const size_t need = 4096 + (mA + mP) * 2048;
    __bf16* hA; __bf16* hP; int hstride, inplace;
    if (ws_size >= need) {
        hA = (__bf16*)((char*)d_ws + 4096);
        hP = hA + mA * 1024;
        hstride = 1024; inplace = 0;
    } else {
        hA = (__bf16*)out_atom;
        hP = (__bf16*)out_pair;
        hstride = 2048; inplace = 1;
    }

    (void)hipMemsetAsync(d_ws, 0, 256 * sizeof(float), stream);

    // Pass 1 (merged): grid split proportional to tile counts.
    const int tA = (N + 31) / 32, tP = (E + 31) / 32;
    int aB = imax(1, (int)((long long)1792 * tA / (tA + tP)));
    aB = imin(aB, imax(1, (tA + 3) / 4));
    int pB = imin(1792 - aB, imax(1, (tP + 3) / 4));
    pass1_kernel<<<aB + pB, 256, 0, stream>>>(
        x, W_atom, b_atom, N, pf, W_pair, b_pair, E,
        stats, hA, hP, hstride, aB);

    finalize_stats_kernel<<<1, 128, 0, stream>>>(stats, g_atom, be_atom,
                                                 g_pair, be_pair,
                                                 (float)N, (float)E, params);

    // Pass 2 (merged): pair tiles weighted ~2x atom tiles.
    const int t16a = (N + 15) / 16, t16p = E / 16;
    int aB2 = imax(1, (int)((long long)1920 * t16a / (t16a + 2 * (long long)t16p)));
    aB2 = imin(aB2, imax(1, (t16a + 3) / 4));
    int pB2 = imin(1920 - aB2, imax(1, (t16p + 3) / 4));
    pass2_kernel<<<aB2 + pB2, 256, 0, stream>>>(
        out_atom, hA, N, out_pair, hP, E,
        x, pidx, W_a2p, b_a2p, params, hstride, aB2, inplace);
}